// Round 11
// baseline (123.252 us; speedup 1.0000x reference)
//
#include <hip/hip_runtime.h>
#include <math.h>

#define K_ 32
#define D_ 8
#define NF 48
#define NTHREADS 256
#define TPW 2          // tiles per wave
#define NBLOCKS 2048   // 2048 blk * 4 waves * 2 tiles = 16384 tiles = N/32

typedef _Float16 half8 __attribute__((ext_vector_type(8)));
typedef float f32x16 __attribute__((ext_vector_type(16)));

// ---------------------------------------------------------------------------
// Precompute kernel (one wave): per-component MFMA A-operand fragments -> ws.
// maha = x^T A x - 2 b^T x + mu^T b, A = L^-T L^-1 (chol(LL^T+epsI) = L*sign,
// sign-invariant). Log2 domain, alpha = 0.5*log2e:
//   W2[n][k] = sum_f V[k][f] Y[n][f],  Y = [x_i x_j (j<=i), x_i, 1, pad3]
// A-frag layout for v_mfma_f32_32x32x16_f16 step s: lane l holds
// V[k=l&31][16s + 8*(l>>5) + j], j=0..7  ->  ws_half[s*512 + l*8 + j].
// ---------------------------------------------------------------------------
__global__ void gmm_precompute(const float* __restrict__ pi,
                               const float* __restrict__ means,
                               const float* __restrict__ chol,
                               _Float16* __restrict__ wsA) {
    const int l = threadIdx.x;
    const int k = l & 31;

    float L[D_][D_];
#pragma unroll
    for (int i = 0; i < D_; ++i)
#pragma unroll
        for (int j = 0; j <= i; ++j)
            L[i][j] = chol[k * 64 + i * 8 + j];

    float rd[D_];
#pragma unroll
    for (int i = 0; i < D_; ++i) rd[i] = 1.f / L[i][i];

    float Ci[D_][D_];
#pragma unroll
    for (int j = 0; j < D_; ++j) {
        Ci[j][j] = rd[j];
#pragma unroll
        for (int i = j + 1; i < D_; ++i) {
            float s = 0.f;
#pragma unroll
            for (int m = j; m < i; ++m) s += L[i][m] * Ci[m][j];
            Ci[i][j] = -s * rd[i];
        }
    }

    float logdet = 0.f;
#pragma unroll
    for (int i = 0; i < D_; ++i) logdet += __logf(fabsf(L[i][i]));
    logdet *= 2.f;

    float A2[D_][D_];
#pragma unroll
    for (int i = 0; i < D_; ++i)
#pragma unroll
        for (int j = 0; j <= i; ++j) {
            float s = 0.f;
#pragma unroll
            for (int m = i; m < D_; ++m) s += Ci[m][i] * Ci[m][j];
            A2[i][j] = s;
            A2[j][i] = s;
        }

    float mu[D_];
#pragma unroll
    for (int j = 0; j < D_; ++j) mu[j] = means[k * 8 + j];
    float b[D_], q = 0.f;
#pragma unroll
    for (int i = 0; i < D_; ++i) {
        float s = 0.f;
#pragma unroll
        for (int j = 0; j < D_; ++j) s += A2[i][j] * mu[j];
        b[i] = s;
        q += s * mu[i];
    }

    float mx = pi[0];
#pragma unroll
    for (int t = 1; t < K_; ++t) mx = fmaxf(mx, pi[t]);
    float se = 0.f;
#pragma unroll
    for (int t = 0; t < K_; ++t) se += __expf(pi[t] - mx);
    float lse = mx + __logf(se);

    const float LOG2PI = 1.8378770664093453f;
    const float LOG2E  = 1.4426950408889634f;
    const float ALPHA  = 0.72134752044448170f;  // 0.5 * log2e
    float cst2 = ((pi[k] - lse) - 0.5f * (logdet + 8.f * LOG2PI)) * LOG2E;

    float V[NF];
    int t = 0;
#pragma unroll
    for (int i = 0; i < D_; ++i)
#pragma unroll
        for (int j = 0; j <= i; ++j)
            V[t++] = (i == j) ? -ALPHA * A2[i][i] : -2.f * ALPHA * A2[i][j];
#pragma unroll
    for (int i = 0; i < D_; ++i) V[36 + i] = 2.f * ALPHA * b[i];
    V[44] = cst2 - ALPHA * q;
    V[45] = 0.f; V[46] = 0.f; V[47] = 0.f;

    const int h = l >> 5;
#pragma unroll
    for (int s = 0; s < 3; ++s)
#pragma unroll
        for (int j = 0; j < 8; ++j)
            wsA[s * 512 + l * 8 + j] = (_Float16)V[16 * s + 8 * h + j];
}

// ---------------------------------------------------------------------------
// Main kernel. No LDS, no barrier, no per-block precompute (round-10 lesson:
// per-block serial phase-1 + VGPR-pressure-induced load re-sinking kept the
// kernel ~5x above model). Each lane computes only the 24 features its
// half-wave feeds into the B-operand; ~90 VGPR -> 5+ waves/SIMD so TLP hides
// HBM latency. 3x v_mfma_f32_32x32x16_f16; C row = component, col = sample;
// k-reduce = 16 exp2 + 15 adds in-lane + shfl_xor(32); coalesced half store.
// ---------------------------------------------------------------------------
__global__ __launch_bounds__(NTHREADS) void gmm_mfma(
    const float* __restrict__ x,
    const _Float16* __restrict__ wsA,
    float* __restrict__ out, int N)
{
    const int tid  = threadIdx.x;
    const int lane = tid & 63;
    const int m    = lane & 31;
    const int h    = lane >> 5;   // which 8-feature half of each 16-block

    // one-time A-fragment load: 3 x 16B per lane, contiguous per step
    half8 wf[3];
#pragma unroll
    for (int s = 0; s < 3; ++s)
        wf[s] = *(const half8*)(wsA + s * 512 + lane * 8);

    const int w  = blockIdx.x * (NTHREADS / 64) + (tid >> 6);
    const int t0 = w * TPW;
    const float4* xp = (const float4*)x;
    const float LN2 = 0.69314718055994531f;

    float xv[TPW][D_];
#pragma unroll
    for (int u = 0; u < TPW; ++u) {
        const int n = (t0 + u) * 32 + m;
        float4 a = xp[2 * n], b2 = xp[2 * n + 1];
        xv[u][0] = a.x;  xv[u][1] = a.y;  xv[u][2] = a.z;  xv[u][3] = a.w;
        xv[u][4] = b2.x; xv[u][5] = b2.y; xv[u][6] = b2.z; xv[u][7] = b2.w;
    }

#pragma unroll
    for (int u = 0; u < TPW; ++u) {
        f32x16 acc;
#pragma unroll
        for (int r = 0; r < 16; ++r) acc[r] = 0.f;

#pragma unroll
        for (int s = 0; s < 3; ++s) {
            half8 bf;
#pragma unroll
            for (int j = 0; j < 8; ++j) {
                const int f = 16 * s + 8 * h + j;   // compile-time per (s,h,j)
                float v;
                if (f < 36) {
                    // triangular index -> (i,j): computed at compile time
                    int fi = 0;
                    while ((fi + 1) * (fi + 2) / 2 <= f) ++fi;
                    int fj = f - fi * (fi + 1) / 2;
                    v = xv[u][fi] * xv[u][fj];
                } else if (f < 44) {
                    v = xv[u][f - 36];
                } else if (f == 44) {
                    v = 1.f;
                } else {
                    v = 0.f;
                }
                bf[j] = (_Float16)v;
            }
            acc = __builtin_amdgcn_mfma_f32_32x32x16_f16(wf[s], bf, acc, 0, 0, 0);
        }

        float tot = 0.f;
#pragma unroll
        for (int r = 0; r < 16; ++r) tot += exp2f(acc[r]);
        tot += __shfl_xor(tot, 32, 64);
        float res = log2f(tot) * LN2;
        if (h == 0) out[(t0 + u) * 32 + m] = res;  // lanes 0..31: 128B store
    }
}

extern "C" void kernel_launch(void* const* d_in, const int* in_sizes, int n_in,
                              void* d_out, int out_size, void* d_ws, size_t ws_size,
                              hipStream_t stream) {
    const float* x     = (const float*)d_in[0];
    const float* pi    = (const float*)d_in[1];
    const float* means = (const float*)d_in[2];
    const float* chol  = (const float*)d_in[3];
    float* out = (float*)d_out;
    _Float16* wsA = (_Float16*)d_ws;   // 3*512 halfs = 3 KB

    int N = in_sizes[0] / D_;

    gmm_precompute<<<1, 64, 0, stream>>>(pi, means, chol, wsA);
    gmm_mfma<<<NBLOCKS, NTHREADS, 0, stream>>>(x, wsA, out, N);
}

// Round 12
// 74.584 us; speedup vs baseline: 1.6525x; 1.6525x over previous
//
#include <hip/hip_runtime.h>
#include <math.h>

#define K_ 32
#define D_ 8
#define NF 48
#define NTHREADS 256
#define TPW 2          // tiles per wave
#define NBLOCKS 2048   // 2048 blk * 4 waves * 2 tiles = 16384 tiles = N/32

typedef _Float16 half8 __attribute__((ext_vector_type(8)));
typedef float f32x16 __attribute__((ext_vector_type(16)));

// ---------------------------------------------------------------------------
// Precompute kernel (one wave): per-component MFMA A-operand fragments -> ws.
// maha = x^T A x - 2 b^T x + mu^T b, A = L^-T L^-1 (chol(LL^T+epsI) = L*sign,
// sign-invariant; eps O(1e-6) rel). Log2 domain, alpha = 0.5*log2e:
//   W2[n][k] = sum_f V[k][f] Y[n][f],  Y = [x_i x_j (j<=i), x_i, 1, pad3]
// A-frag layout for v_mfma_f32_32x32x16_f16 step s: lane l holds
// V[k=l&31][16s + 8*(l>>5) + j], j=0..7  ->  ws_half[s*512 + l*8 + j].
// ---------------------------------------------------------------------------
__global__ void gmm_precompute(const float* __restrict__ pi,
                               const float* __restrict__ means,
                               const float* __restrict__ chol,
                               _Float16* __restrict__ wsA) {
    const int l = threadIdx.x;
    const int k = l & 31;

    float L[D_][D_];
#pragma unroll
    for (int i = 0; i < D_; ++i)
#pragma unroll
        for (int j = 0; j <= i; ++j)
            L[i][j] = chol[k * 64 + i * 8 + j];

    float rd[D_];
#pragma unroll
    for (int i = 0; i < D_; ++i) rd[i] = 1.f / L[i][i];

    float Ci[D_][D_];
#pragma unroll
    for (int j = 0; j < D_; ++j) {
        Ci[j][j] = rd[j];
#pragma unroll
        for (int i = j + 1; i < D_; ++i) {
            float s = 0.f;
#pragma unroll
            for (int m = j; m < i; ++m) s += L[i][m] * Ci[m][j];
            Ci[i][j] = -s * rd[i];
        }
    }

    float logdet = 0.f;
#pragma unroll
    for (int i = 0; i < D_; ++i) logdet += __logf(fabsf(L[i][i]));
    logdet *= 2.f;

    float A2[D_][D_];
#pragma unroll
    for (int i = 0; i < D_; ++i)
#pragma unroll
        for (int j = 0; j <= i; ++j) {
            float s = 0.f;
#pragma unroll
            for (int m = i; m < D_; ++m) s += Ci[m][i] * Ci[m][j];
            A2[i][j] = s;
            A2[j][i] = s;
        }

    float mu[D_];
#pragma unroll
    for (int j = 0; j < D_; ++j) mu[j] = means[k * 8 + j];
    float b[D_], q = 0.f;
#pragma unroll
    for (int i = 0; i < D_; ++i) {
        float s = 0.f;
#pragma unroll
        for (int j = 0; j < D_; ++j) s += A2[i][j] * mu[j];
        b[i] = s;
        q += s * mu[i];
    }

    float mx = pi[0];
#pragma unroll
    for (int t = 1; t < K_; ++t) mx = fmaxf(mx, pi[t]);
    float se = 0.f;
#pragma unroll
    for (int t = 0; t < K_; ++t) se += __expf(pi[t] - mx);
    float lse = mx + __logf(se);

    const float LOG2PI = 1.8378770664093453f;
    const float LOG2E  = 1.4426950408889634f;
    const float ALPHA  = 0.72134752044448170f;  // 0.5 * log2e
    float cst2 = ((pi[k] - lse) - 0.5f * (logdet + 8.f * LOG2PI)) * LOG2E;

    float V[NF];
    int t = 0;
#pragma unroll
    for (int i = 0; i < D_; ++i)
#pragma unroll
        for (int j = 0; j <= i; ++j)
            V[t++] = (i == j) ? -ALPHA * A2[i][i] : -2.f * ALPHA * A2[i][j];
#pragma unroll
    for (int i = 0; i < D_; ++i) V[36 + i] = 2.f * ALPHA * b[i];
    V[44] = cst2 - ALPHA * q;
    V[45] = 0.f; V[46] = 0.f; V[47] = 0.f;

    const int h = l >> 5;
#pragma unroll
    for (int s = 0; s < 3; ++s)
#pragma unroll
        for (int j = 0; j < 8; ++j)
            wsA[s * 512 + l * 8 + j] = (_Float16)V[16 * s + 8 * h + j];
}

// ---- compile-time feature evaluation (round-11 bug: h made f runtime; now
// both half candidates use template-constant indices, selected by 1 cndmask)
constexpr int tri_i(int f) {
    int i = 0;
    while ((i + 1) * (i + 2) / 2 <= f) ++i;
    return i;
}

template <int F>
__device__ __forceinline__ float feat(const float* xv) {
    if constexpr (F < 36) {
        constexpr int i = tri_i(F);
        constexpr int j = F - i * (i + 1) / 2;
        return xv[i] * xv[j];
    } else if constexpr (F < 44) {
        return xv[F - 36];
    } else if constexpr (F == 44) {
        return 1.f;
    } else {
        return 0.f;
    }
}

// bf element j for step s: h ? feature(16s+8+j) : feature(16s+j)
#define BFEL(S, J) \
    bf[J] = (_Float16)(h ? feat<16 * (S) + 8 + (J)>(xq) : feat<16 * (S) + (J)>(xq))
#define BSTEP(S)                                                        \
    {                                                                   \
        half8 bf;                                                       \
        BFEL(S, 0); BFEL(S, 1); BFEL(S, 2); BFEL(S, 3);                 \
        BFEL(S, 4); BFEL(S, 5); BFEL(S, 6); BFEL(S, 7);                 \
        acc = __builtin_amdgcn_mfma_f32_32x32x16_f16(wf[S], bf, acc, 0, 0, 0); \
    }

// ---------------------------------------------------------------------------
// Main kernel. No LDS, no barrier, no per-block precompute. VGPR stays low
// (round-11: 44) -> 8 waves/SIMD; TLP hides HBM latency. 3 MFMAs/tile;
// C row = component, col = sample; k-reduce = 16 exp2 + 15 adds in-lane +
// shfl_xor(32); lanes 0..31 store 128 B coalesced.
// ---------------------------------------------------------------------------
__global__ __launch_bounds__(NTHREADS) void gmm_mfma(
    const float* __restrict__ x,
    const _Float16* __restrict__ wsA,
    float* __restrict__ out, int N)
{
    const int tid  = threadIdx.x;
    const int lane = tid & 63;
    const int m    = lane & 31;
    const int h    = lane >> 5;   // which 8-feature half of each 16-block

    half8 wf[3];
#pragma unroll
    for (int s = 0; s < 3; ++s)
        wf[s] = *(const half8*)(wsA + s * 512 + lane * 8);

    const int w  = blockIdx.x * (NTHREADS / 64) + (tid >> 6);
    const int t0 = w * TPW;
    const float4* xp = (const float4*)x;
    const float LN2 = 0.69314718055994531f;

    float xv[TPW][D_];
#pragma unroll
    for (int u = 0; u < TPW; ++u) {
        const int n = (t0 + u) * 32 + m;
        float4 a = xp[2 * n], b2 = xp[2 * n + 1];
        xv[u][0] = a.x;  xv[u][1] = a.y;  xv[u][2] = a.z;  xv[u][3] = a.w;
        xv[u][4] = b2.x; xv[u][5] = b2.y; xv[u][6] = b2.z; xv[u][7] = b2.w;
    }

#pragma unroll
    for (int u = 0; u < TPW; ++u) {
        const float* xq = xv[u];

        f32x16 acc;
#pragma unroll
        for (int r = 0; r < 16; ++r) acc[r] = 0.f;

        BSTEP(0);
        BSTEP(1);
        BSTEP(2);

        float tot = 0.f;
#pragma unroll
        for (int r = 0; r < 16; ++r) tot += exp2f(acc[r]);
        tot += __shfl_xor(tot, 32, 64);
        float res = log2f(tot) * LN2;
        if (h == 0) out[(t0 + u) * 32 + m] = res;
    }
}

extern "C" void kernel_launch(void* const* d_in, const int* in_sizes, int n_in,
                              void* d_out, int out_size, void* d_ws, size_t ws_size,
                              hipStream_t stream) {
    const float* x     = (const float*)d_in[0];
    const float* pi    = (const float*)d_in[1];
    const float* means = (const float*)d_in[2];
    const float* chol  = (const float*)d_in[3];
    float* out = (float*)d_out;
    _Float16* wsA = (_Float16*)d_ws;   // 3*512 halfs = 3 KB

    int N = in_sizes[0] / D_;

    gmm_precompute<<<1, 64, 0, stream>>>(pi, means, chol, wsA);
    gmm_mfma<<<NBLOCKS, NTHREADS, 0, stream>>>(x, wsA, out, N);
}